// Round 3
// baseline (217.057 us; speedup 1.0000x reference)
//
#include <hip/hip_runtime.h>
#include <cstdint>

typedef unsigned long long u64;
typedef uint32_t u32;

#define NB 2048
#define CAND_CAP 65536
#define EDGE_CAP 16384
#define EDGE_LDS 16384

// ---------------------------------------------------------------------------
// Faithful f32 replication of the reference geometry. contract(off) so we
// match XLA's separate mul/add rounding (no fma contraction).
// ---------------------------------------------------------------------------

__device__ __forceinline__ bool pt_in(float px, float py, float cx, float cy,
                                      float hw, float hh, float c, float s) {
#pragma clang fp contract(off)
  float ax = px - cx;
  float ay = py - cy;
  float lx = c * ax + s * ay;
  float ly = c * ay - s * ax;
  return (fabsf(lx) <= hw + 1e-5f) && (fabsf(ly) <= hh + 1e-5f);
}

__device__ float pair_inter_area(float acx, float acy, float aw, float ah,
                                 float ac, float as_, float bcx, float bcy,
                                 float bw, float bh, float bc, float bs_) {
#pragma clang fp contract(off)
  const float SX[4] = {-1.f, 1.f, 1.f, -1.f};
  const float SY[4] = {-1.f, -1.f, 1.f, 1.f};
  float axx[4], ayy[4], bxx[4], byy[4];
  float ahw = aw * 0.5f, ahh = ah * 0.5f;
  float bhw = bw * 0.5f, bhh = bh * 0.5f;
#pragma unroll
  for (int q = 0; q < 4; ++q) {
    float dx = SX[q] * ahw, dy = SY[q] * ahh;
    axx[q] = acx + ac * dx - as_ * dy;
    ayy[q] = acy + as_ * dx + ac * dy;
    float ex = SX[q] * bhw, ey = SY[q] * bhh;
    bxx[q] = bcx + bc * ex - bs_ * ey;
    byy[q] = bcy + bs_ * ex + bc * ey;
  }
  float px_[24], py_[24];
  bool mk[24];
#pragma unroll
  for (int q = 0; q < 4; ++q) {
    px_[q] = axx[q]; py_[q] = ayy[q];
    mk[q] = pt_in(axx[q], ayy[q], bcx, bcy, bhw, bhh, bc, bs_);
    px_[4 + q] = bxx[q]; py_[4 + q] = byy[q];
    mk[4 + q] = pt_in(bxx[q], byy[q], acx, acy, ahw, ahh, ac, as_);
  }
#pragma unroll
  for (int e = 0; e < 4; ++e) {
    float rx = axx[(e + 1) & 3] - axx[e];
    float ry = ayy[(e + 1) & 3] - ayy[e];
#pragma unroll
    for (int f = 0; f < 4; ++f) {
      float sx = bxx[(f + 1) & 3] - bxx[f];
      float sy = byy[(f + 1) & 3] - byy[f];
      float denom = rx * sy - ry * sx;
      float qpx = bxx[f] - axx[e];
      float qpy = byy[f] - ayy[e];
      bool dn = fabsf(denom) > 1e-9f;
      float safe = dn ? denom : 1.0f;
      float t = (qpx * sy - qpy * sx) / safe;
      float uu = (qpx * ry - qpy * rx) / safe;
      bool valid = dn && (t >= 0.0f) && (t <= 1.0f) && (uu >= 0.0f) && (uu <= 1.0f);
      int id = 8 + e * 4 + f;
      px_[id] = axx[e] + t * rx;
      py_[id] = ayy[e] + t * ry;
      mk[id] = valid;
    }
  }
  int k = 0;
  float sx0 = 0.0f, sy0 = 0.0f;
#pragma unroll
  for (int q = 0; q < 24; ++q) {
    if (mk[q]) { k++; sx0 += px_[q]; sy0 += py_[q]; }
  }
  float kk = (float)(k > 0 ? k : 1);
  float cxm = sx0 / kk, cym = sy0 / kk;
  u64 key[24];
  float dxr[24], dyr[24];
#pragma unroll
  for (int q = 0; q < 24; ++q) {
    float dx = px_[q] - cxm, dy = py_[q] - cym;
    dxr[q] = dx; dyr[q] = dy;
    float ang = mk[q] ? atan2f(dy, dx) : 1e9f;
    u32 ub = __float_as_uint(ang);
    u32 v = (ub & 0x80000000u) ? ~ub : (ub | 0x80000000u);
    key[q] = (((u64)v) << 5) | (u64)q;
  }
  for (int a = 1; a < 24; ++a) {
    u64 kv = key[a];
    float dx = dxr[a], dy = dyr[a];
    int b = a - 1;
    while (b >= 0 && key[b] > kv) {
      key[b + 1] = key[b]; dxr[b + 1] = dxr[b]; dyr[b + 1] = dyr[b];
      --b;
    }
    key[b + 1] = kv; dxr[b + 1] = dx; dyr[b + 1] = dy;
  }
  float acc = 0.0f;
  for (int q = 0; q < 24; ++q) {
    if (q < k) {
      int n2 = (q + 1 < k) ? q + 1 : 0;
      acc += dxr[q] * dyr[n2] - dyr[q] * dxr[n2];
    }
  }
  float area = 0.5f * fabsf(acc);
  return (k >= 3) ? area : 0.0f;
}

// ---------------------------------------------------------------------------
// A: fused reduce (offset_scale, per-block redundant) + stable rank sort +
//    sorted SoA write + counter zeroing.
// ---------------------------------------------------------------------------
__global__ __launch_bounds__(256) void build_kernel(
    const float* __restrict__ boxes, const float* __restrict__ scores,
    const int* __restrict__ labels,
    float* __restrict__ cxp, float* __restrict__ cyp, float* __restrict__ wp,
    float* __restrict__ hp, float* __restrict__ cp, float* __restrict__ sp,
    float* __restrict__ radp, float* __restrict__ sscp, int* __restrict__ sidx,
    u32* __restrict__ counters) {
#pragma clang fp contract(off)
  __shared__ float sc[NB];
  __shared__ float smc[4], smr[4];
  int t = threadIdx.x;
  int i = blockIdx.x * 256 + t;
  if (blockIdx.x == 0 && t < 2) counters[t] = 0u;
  // redundant per-block reduction over all boxes
  float mc = -1e30f, mr = -1e30f;
  for (int k = t; k < NB; k += 256) {
    float cx = boxes[k * 5 + 0];
    float cy = boxes[k * 5 + 1];
    float w = boxes[k * 5 + 2];
    float h = boxes[k * 5 + 3];
    mc = fmaxf(mc, fmaxf(cx, cy));
    float ww = w * w;
    float hh = h * h;
    mr = fmaxf(mr, sqrtf(ww + hh));
    sc[k] = scores[k];
  }
  for (int off = 32; off > 0; off >>= 1) {
    mc = fmaxf(mc, __shfl_down(mc, off));
    mr = fmaxf(mr, __shfl_down(mr, off));
  }
  if ((t & 63) == 0) { smc[t >> 6] = mc; smr[t >> 6] = mr; }
  __syncthreads();
  mc = fmaxf(fmaxf(smc[0], smc[1]), fmaxf(smc[2], smc[3]));
  mr = fmaxf(fmaxf(smr[0], smr[1]), fmaxf(smr[2], smr[3]));
  float osc = (mc + mr * 0.5f) * 2.0f + 1.0f;

  float si = sc[i];
  int rank = 0;
  const float4* sc4 = (const float4*)sc;
#pragma unroll 4
  for (int j4 = 0; j4 < NB / 4; ++j4) {
    float4 v = sc4[j4];
    int j = j4 * 4;
    rank += (int)((v.x > si) || (v.x == si && (j + 0) < i));
    rank += (int)((v.y > si) || (v.y == si && (j + 1) < i));
    rank += (int)((v.z > si) || (v.z == si && (j + 2) < i));
    rank += (int)((v.w > si) || (v.w == si && (j + 3) < i));
  }
  float off = (float)labels[i] * osc;
  float cx = boxes[i * 5 + 0] + off;
  float cy = boxes[i * 5 + 1] + off;
  float w = boxes[i * 5 + 2];
  float h = boxes[i * 5 + 3];
  float a = boxes[i * 5 + 4];
  float c = cosf(a);
  float s = sinf(a);
  float ww = w * w;
  float hh = h * h;
  cxp[rank] = cx;
  cyp[rank] = cy;
  wp[rank] = w;
  hp[rank] = h;
  cp[rank] = c;
  sp[rank] = s;
  radp[rank] = 0.5f * sqrtf(ww + hh);
  sscp[rank] = si;
  sidx[rank] = i;
}

// ---------------------------------------------------------------------------
// B: candidate generation. 256 blocks x 8 rows; circle test from LDS; passing
//    (i,j) pairs (j>i) appended to compact list.
// ---------------------------------------------------------------------------
__global__ __launch_bounds__(256) void cand_kernel(
    const float* __restrict__ cxp, const float* __restrict__ cyp,
    const float* __restrict__ radp, u32* __restrict__ cand,
    u32* __restrict__ counters) {
#pragma clang fp contract(off)
  __shared__ float lx[NB], ly[NB], lr[NB];
  int t = threadIdx.x;
  for (int k = t; k < NB; k += 256) {
    lx[k] = cxp[k];
    ly[k] = cyp[k];
    lr[k] = radp[k];
  }
  __syncthreads();
  int i0 = blockIdx.x * 8;
#pragma unroll
  for (int di = 0; di < 8; ++di) {
    int i = i0 + di;
    float ax = lx[i], ay = ly[i], ar = lr[i];
#pragma unroll
    for (int c = 0; c < 8; ++c) {
      int j = c * 256 + t;
      bool hit = false;
      if (j > i) {
        float dx = lx[j] - ax, dy = ly[j] - ay;
        float rr = ar + lr[j] + 1.0f;
        hit = (dx * dx + dy * dy <= rr * rr);
      }
      if (hit) {
        u32 dst = atomicAdd(&counters[0], 1u);
        if (dst < CAND_CAP) cand[dst] = ((u32)i << 16) | (u32)j;
      }
    }
  }
}

// ---------------------------------------------------------------------------
// C: full rotated-IoU on candidates only; suppression edges appended.
// ---------------------------------------------------------------------------
__global__ __launch_bounds__(256) void geom_kernel(
    const float* __restrict__ cxp, const float* __restrict__ cyp,
    const float* __restrict__ wp, const float* __restrict__ hp,
    const float* __restrict__ cp, const float* __restrict__ sp,
    const float* __restrict__ thrp, const u32* __restrict__ cand,
    u32* __restrict__ edges, u32* __restrict__ counters) {
#pragma clang fp contract(off)
  u32 cnt = counters[0];
  if (cnt > CAND_CAP) cnt = CAND_CAP;
  float thr = *thrp;
  for (u32 idx = blockIdx.x * 256 + threadIdx.x; idx < cnt; idx += 32 * 256) {
    u32 pk = cand[idx];
    int i = (int)(pk >> 16);
    int j = (int)(pk & 0xFFFFu);
    float acx = cxp[i], acy = cyp[i], aw = wp[i], ah = hp[i];
    float ac = cp[i], as_ = sp[i];
    float bcx = cxp[j], bcy = cyp[j], bw = wp[j], bh = hp[j];
    float bc = cp[j], bs_ = sp[j];
    float inter = pair_inter_area(acx, acy, aw, ah, ac, as_,
                                  bcx, bcy, bw, bh, bc, bs_);
    float areaA = aw * ah;
    float areaB = bw * bh;
    float iou = inter / (areaA + areaB - inter + 1e-9f);
    if (iou > thr) {
      u32 e = atomicAdd(&counters[1], 1u);
      if (e < EDGE_CAP) edges[e] = pk;
    }
  }
}

// ---------------------------------------------------------------------------
// D: greedy keep as parallel fixpoint over the sparse edge list (LDS-staged),
//    then fused output scatter. Antitone F => converges to the exact
//    sequential-greedy fixpoint.
// ---------------------------------------------------------------------------
__global__ __launch_bounds__(256) void greedy_out_kernel(
    const u32* __restrict__ edges, const u32* __restrict__ counters,
    const float* __restrict__ sscp, const int* __restrict__ sidx,
    float* __restrict__ out) {
  __shared__ u64 keepw[32];
  __shared__ u32 Sw32[64];
  __shared__ int changed;
  __shared__ u32 eL[EDGE_LDS];
  int t = threadIdx.x;
  u32 ecnt = counters[1];
  if (ecnt > EDGE_CAP) ecnt = EDGE_CAP;
  u32 nl = ecnt < EDGE_LDS ? ecnt : EDGE_LDS;
  for (u32 k = t; k < nl; k += 256) eL[k] = edges[k];
  if (t < 32) keepw[t] = ~0ull;
  __syncthreads();
  for (int iter = 0; iter < 2060; ++iter) {
    if (t < 64) Sw32[t] = 0u;
    if (t == 0) changed = 0;
    __syncthreads();
    for (u32 k = t; k < ecnt; k += 256) {
      u32 pk = (k < EDGE_LDS) ? eL[k] : edges[k];
      int i = (int)(pk >> 16);
      int j = (int)(pk & 0xFFFFu);
      if ((keepw[i >> 6] >> (i & 63)) & 1ull)
        atomicOr(&Sw32[j >> 5], 1u << (j & 31));
    }
    __syncthreads();
    if (t < 32) {
      u64 S = ((u64)Sw32[2 * t]) | (((u64)Sw32[2 * t + 1]) << 32);
      u64 nk = ~S;
      if (nk != keepw[t]) { keepw[t] = nk; changed = 1; }
    }
    __syncthreads();
    int ch = changed;
    __syncthreads();
    if (!ch) break;
  }
  for (int p = t; p < NB; p += 256) {
    int bit = (int)((keepw[p >> 6] >> (p & 63)) & 1ull);
    out[sidx[p]] = bit ? sscp[p] : 0.0f;
  }
}

extern "C" void kernel_launch(void* const* d_in, const int* in_sizes, int n_in,
                              void* d_out, int out_size, void* d_ws, size_t ws_size,
                              hipStream_t stream) {
  const float* boxes = (const float*)d_in[0];
  const float* scores = (const float*)d_in[1];
  const int* labels = (const int*)d_in[2];
  const float* thr = (const float*)d_in[3];
  float* out = (float*)d_out;

  char* base = (char*)d_ws;
  u32* counters = (u32*)base;                       // 2 u32 (pad 256)
  float* arr = (float*)(base + 256);                // 8 x 2048 f32 = 64 KB
  float* cxp = arr + 0 * NB;
  float* cyp = arr + 1 * NB;
  float* wp = arr + 2 * NB;
  float* hp = arr + 3 * NB;
  float* cp = arr + 4 * NB;
  float* sp = arr + 5 * NB;
  float* radp = arr + 6 * NB;
  float* sscp = arr + 7 * NB;
  int* sidx = (int*)(base + 66048);                 // 8 KB, ends 74240
  u32* cand = (u32*)(base + 81920);                 // 256 KB, ends 344064
  u32* edges = (u32*)(base + 344064);               // 64 KB, ends 409600

  build_kernel<<<8, 256, 0, stream>>>(boxes, scores, labels, cxp, cyp, wp, hp,
                                      cp, sp, radp, sscp, sidx, counters);
  cand_kernel<<<256, 256, 0, stream>>>(cxp, cyp, radp, cand, counters);
  geom_kernel<<<32, 256, 0, stream>>>(cxp, cyp, wp, hp, cp, sp, thr, cand,
                                      edges, counters);
  greedy_out_kernel<<<1, 256, 0, stream>>>(edges, counters, sscp, sidx, out);
}

// Round 4
// 136.476 us; speedup vs baseline: 1.5904x; 1.5904x over previous
//
#include <hip/hip_runtime.h>
#include <cstdint>

typedef unsigned long long u64;
typedef uint32_t u32;

#define NB 2048
#define EDGE_CAP 16384
#define EDGE_LDS 16384
#define CLIST_CAP 2048

// ---------------------------------------------------------------------------
// Faithful f32 replication of the reference geometry. contract(off) so we
// match XLA's separate mul/add rounding. ALL array indexing is static after
// full unroll -> everything lives in VGPRs (no scratch).
// ---------------------------------------------------------------------------

__device__ __forceinline__ bool pt_in(float px, float py, float cx, float cy,
                                      float hw, float hh, float c, float s) {
#pragma clang fp contract(off)
  float ax = px - cx;
  float ay = py - cy;
  float lx = c * ax + s * ay;
  float ly = c * ay - s * ax;
  return (fabsf(lx) <= hw + 1e-5f) && (fabsf(ly) <= hh + 1e-5f);
}

__device__ float pair_inter_area(float acx, float acy, float aw, float ah,
                                 float ac, float as_, float bcx, float bcy,
                                 float bw, float bh, float bc, float bs_) {
#pragma clang fp contract(off)
  const float SX[4] = {-1.f, 1.f, 1.f, -1.f};
  const float SY[4] = {-1.f, -1.f, 1.f, 1.f};
  float axx[4], ayy[4], bxx[4], byy[4];
  float ahw = aw * 0.5f, ahh = ah * 0.5f;
  float bhw = bw * 0.5f, bhh = bh * 0.5f;
#pragma unroll
  for (int q = 0; q < 4; ++q) {
    float dx = SX[q] * ahw, dy = SY[q] * ahh;
    axx[q] = acx + ac * dx - as_ * dy;
    ayy[q] = acy + as_ * dx + ac * dy;
    float ex = SX[q] * bhw, ey = SY[q] * bhh;
    bxx[q] = bcx + bc * ex - bs_ * ey;
    byy[q] = bcy + bs_ * ex + bc * ey;
  }
  float px_[24], py_[24];
  bool mk[24];
#pragma unroll
  for (int q = 0; q < 4; ++q) {
    px_[q] = axx[q]; py_[q] = ayy[q];
    mk[q] = pt_in(axx[q], ayy[q], bcx, bcy, bhw, bhh, bc, bs_);
    px_[4 + q] = bxx[q]; py_[4 + q] = byy[q];
    mk[4 + q] = pt_in(bxx[q], byy[q], acx, acy, ahw, ahh, ac, as_);
  }
#pragma unroll
  for (int e = 0; e < 4; ++e) {
    float rx = axx[(e + 1) & 3] - axx[e];
    float ry = ayy[(e + 1) & 3] - ayy[e];
#pragma unroll
    for (int f = 0; f < 4; ++f) {
      float sx = bxx[(f + 1) & 3] - bxx[f];
      float sy = byy[(f + 1) & 3] - byy[f];
      float denom = rx * sy - ry * sx;
      float qpx = bxx[f] - axx[e];
      float qpy = byy[f] - ayy[e];
      bool dn = fabsf(denom) > 1e-9f;
      float safe = dn ? denom : 1.0f;
      float t = (qpx * sy - qpy * sx) / safe;
      float uu = (qpx * ry - qpy * rx) / safe;
      bool valid = dn && (t >= 0.0f) && (t <= 1.0f) && (uu >= 0.0f) && (uu <= 1.0f);
      int id = 8 + e * 4 + f;
      px_[id] = axx[e] + t * rx;
      py_[id] = ayy[e] + t * ry;
      mk[id] = valid;
    }
  }
  int k = 0;
  float sx0 = 0.0f, sy0 = 0.0f;
#pragma unroll
  for (int q = 0; q < 24; ++q) {
    if (mk[q]) { k++; sx0 += px_[q]; sy0 += py_[q]; }
  }
  float kk = (float)(k > 0 ? k : 1);
  float cxm = sx0 / kk, cym = sy0 / kk;
  // 32-slot register-resident arrays; slots 24..31 are +inf pads.
  u64 key[32];
  float dxr[32], dyr[32];
#pragma unroll
  for (int q = 0; q < 24; ++q) {
    float dx = px_[q] - cxm, dy = py_[q] - cym;
    dxr[q] = dx; dyr[q] = dy;
    float ang = mk[q] ? atan2f(dy, dx) : 1e9f;
    u32 ub = __float_as_uint(ang);
    u32 v = (ub & 0x80000000u) ? ~ub : (ub | 0x80000000u);
    key[q] = (((u64)v) << 5) | (u64)q;
  }
#pragma unroll
  for (int q = 24; q < 32; ++q) { key[q] = ~0ull; dxr[q] = 0.f; dyr[q] = 0.f; }
  // Bitonic sorting network, ascending by key. All indices compile-time ->
  // pure v_cmp/v_cndmask, zero scratch. Distinct keys => exact stable-argsort
  // permutation of the reference.
#pragma unroll
  for (int kk2 = 2; kk2 <= 32; kk2 <<= 1) {
#pragma unroll
    for (int jj = kk2 >> 1; jj > 0; jj >>= 1) {
#pragma unroll
      for (int ii = 0; ii < 32; ++ii) {
        int ll = ii ^ jj;
        if (ll > ii) {
          bool up = ((ii & kk2) == 0);
          u64 ka = key[ii], kb = key[ll];
          bool sw = up ? (ka > kb) : (ka < kb);
          key[ii] = sw ? kb : ka;
          key[ll] = sw ? ka : kb;
          float da = dxr[ii], db = dxr[ll];
          dxr[ii] = sw ? db : da;
          dxr[ll] = sw ? da : db;
          float ea = dyr[ii], eb = dyr[ll];
          dyr[ii] = sw ? eb : ea;
          dyr[ll] = sw ? ea : eb;
        }
      }
    }
  }
  float acc = 0.0f;
#pragma unroll
  for (int q = 0; q < 24; ++q) {
    if (q < k - 1) {
      acc += dxr[q] * dyr[q + 1] - dyr[q] * dxr[q + 1];
    } else if (q == k - 1) {
      acc += dxr[q] * dyr[0] - dyr[q] * dxr[0];
    }
  }
  float area = 0.5f * fabsf(acc);
  return (k >= 3) ? area : 0.0f;
}

// ---------------------------------------------------------------------------
// A: fused reduce (offset_scale, per-block redundant) + stable rank sort +
//    sorted SoA write + counter zeroing.
// ---------------------------------------------------------------------------
__global__ __launch_bounds__(256) void build_kernel(
    const float* __restrict__ boxes, const float* __restrict__ scores,
    const int* __restrict__ labels,
    float* __restrict__ cxp, float* __restrict__ cyp, float* __restrict__ wp,
    float* __restrict__ hp, float* __restrict__ cp, float* __restrict__ sp,
    float* __restrict__ radp, float* __restrict__ sscp, int* __restrict__ sidx,
    u32* __restrict__ counters) {
#pragma clang fp contract(off)
  __shared__ float sc[NB];
  __shared__ float smc[4], smr[4];
  int t = threadIdx.x;
  int i = blockIdx.x * 256 + t;
  if (blockIdx.x == 0 && t < 2) counters[t] = 0u;
  float mc = -1e30f, mr = -1e30f;
  for (int k = t; k < NB; k += 256) {
    float cx = boxes[k * 5 + 0];
    float cy = boxes[k * 5 + 1];
    float w = boxes[k * 5 + 2];
    float h = boxes[k * 5 + 3];
    mc = fmaxf(mc, fmaxf(cx, cy));
    float ww = w * w;
    float hh = h * h;
    mr = fmaxf(mr, sqrtf(ww + hh));
    sc[k] = scores[k];
  }
  for (int off = 32; off > 0; off >>= 1) {
    mc = fmaxf(mc, __shfl_down(mc, off));
    mr = fmaxf(mr, __shfl_down(mr, off));
  }
  if ((t & 63) == 0) { smc[t >> 6] = mc; smr[t >> 6] = mr; }
  __syncthreads();
  mc = fmaxf(fmaxf(smc[0], smc[1]), fmaxf(smc[2], smc[3]));
  mr = fmaxf(fmaxf(smr[0], smr[1]), fmaxf(smr[2], smr[3]));
  float osc = (mc + mr * 0.5f) * 2.0f + 1.0f;

  float si = sc[i];
  int rank = 0;
  const float4* sc4 = (const float4*)sc;
#pragma unroll 4
  for (int j4 = 0; j4 < NB / 4; ++j4) {
    float4 v = sc4[j4];
    int j = j4 * 4;
    rank += (int)((v.x > si) || (v.x == si && (j + 0) < i));
    rank += (int)((v.y > si) || (v.y == si && (j + 1) < i));
    rank += (int)((v.z > si) || (v.z == si && (j + 2) < i));
    rank += (int)((v.w > si) || (v.w == si && (j + 3) < i));
  }
  float off = (float)labels[i] * osc;
  float cx = boxes[i * 5 + 0] + off;
  float cy = boxes[i * 5 + 1] + off;
  float w = boxes[i * 5 + 2];
  float h = boxes[i * 5 + 3];
  float a = boxes[i * 5 + 4];
  float c = cosf(a);
  float s = sinf(a);
  float ww = w * w;
  float hh = h * h;
  cxp[rank] = cx;
  cyp[rank] = cy;
  wp[rank] = w;
  hp[rank] = h;
  cp[rank] = c;
  sp[rank] = s;
  radp[rank] = 0.5f * sqrtf(ww + hh);
  sscp[rank] = si;
  sidx[rank] = i;
}

// ---------------------------------------------------------------------------
// B+C fused: per-block candidate generation (8 rows, circle test from LDS,
// LDS list) then full rotated-IoU on own candidates; edges appended globally.
// ---------------------------------------------------------------------------
__global__ __launch_bounds__(256) void candgeom_kernel(
    const float* __restrict__ cxp, const float* __restrict__ cyp,
    const float* __restrict__ wp, const float* __restrict__ hp,
    const float* __restrict__ cp, const float* __restrict__ sp,
    const float* __restrict__ radp, const float* __restrict__ thrp,
    u32* __restrict__ edges, u32* __restrict__ counters) {
#pragma clang fp contract(off)
  __shared__ float lx[NB], ly[NB], lr[NB];
  __shared__ u32 clist[CLIST_CAP];
  __shared__ u32 ccnt;
  int t = threadIdx.x;
  if (t == 0) ccnt = 0;
  for (int k = t; k < NB; k += 256) {
    lx[k] = cxp[k];
    ly[k] = cyp[k];
    lr[k] = radp[k];
  }
  __syncthreads();
  int i0 = blockIdx.x * 8;
#pragma unroll
  for (int di = 0; di < 8; ++di) {
    int i = i0 + di;
    float ax = lx[i], ay = ly[i], ar = lr[i];
#pragma unroll
    for (int c = 0; c < 8; ++c) {
      int j = c * 256 + t;
      if (j > i) {
        float dx = lx[j] - ax, dy = ly[j] - ay;
        float rr = ar + lr[j] + 1.0f;   // conservative circle pre-test
        if (dx * dx + dy * dy <= rr * rr) {
          u32 s = atomicAdd(&ccnt, 1u);
          if (s < CLIST_CAP) clist[s] = ((u32)i << 16) | (u32)j;
        }
      }
    }
  }
  __syncthreads();
  u32 cnt = ccnt < CLIST_CAP ? ccnt : CLIST_CAP;
  float thr = *thrp;
  for (u32 idx = t; idx < cnt; idx += 256) {
    u32 pk = clist[idx];
    int i = (int)(pk >> 16);
    int j = (int)(pk & 0xFFFFu);
    float acx = cxp[i], acy = cyp[i], aw = wp[i], ah = hp[i];
    float ac = cp[i], as_ = sp[i];
    float bcx = cxp[j], bcy = cyp[j], bw = wp[j], bh = hp[j];
    float bc = cp[j], bs_ = sp[j];
    float inter = pair_inter_area(acx, acy, aw, ah, ac, as_,
                                  bcx, bcy, bw, bh, bc, bs_);
    float areaA = aw * ah;
    float areaB = bw * bh;
    float iou = inter / (areaA + areaB - inter + 1e-9f);
    if (iou > thr) {
      u32 e = atomicAdd(&counters[1], 1u);
      if (e < EDGE_CAP) edges[e] = pk;
    }
  }
}

// ---------------------------------------------------------------------------
// D: greedy keep as parallel fixpoint over the sparse edge list (LDS-staged),
//    then fused output scatter. Antitone F => exact sequential-greedy fixpoint.
// ---------------------------------------------------------------------------
__global__ __launch_bounds__(256) void greedy_out_kernel(
    const u32* __restrict__ edges, const u32* __restrict__ counters,
    const float* __restrict__ sscp, const int* __restrict__ sidx,
    float* __restrict__ out) {
  __shared__ u64 keepw[32];
  __shared__ u32 Sw32[64];
  __shared__ int changed;
  __shared__ u32 eL[EDGE_LDS];
  int t = threadIdx.x;
  u32 ecnt = counters[1];
  if (ecnt > EDGE_CAP) ecnt = EDGE_CAP;
  u32 nl = ecnt < EDGE_LDS ? ecnt : EDGE_LDS;
  for (u32 k = t; k < nl; k += 256) eL[k] = edges[k];
  if (t < 32) keepw[t] = ~0ull;
  __syncthreads();
  for (int iter = 0; iter < 2060; ++iter) {
    if (t < 64) Sw32[t] = 0u;
    if (t == 0) changed = 0;
    __syncthreads();
    for (u32 k = t; k < ecnt; k += 256) {
      u32 pk = (k < EDGE_LDS) ? eL[k] : edges[k];
      int i = (int)(pk >> 16);
      int j = (int)(pk & 0xFFFFu);
      if ((keepw[i >> 6] >> (i & 63)) & 1ull)
        atomicOr(&Sw32[j >> 5], 1u << (j & 31));
    }
    __syncthreads();
    if (t < 32) {
      u64 S = ((u64)Sw32[2 * t]) | (((u64)Sw32[2 * t + 1]) << 32);
      u64 nk = ~S;
      if (nk != keepw[t]) { keepw[t] = nk; changed = 1; }
    }
    __syncthreads();
    int ch = changed;
    __syncthreads();
    if (!ch) break;
  }
  for (int p = t; p < NB; p += 256) {
    int bit = (int)((keepw[p >> 6] >> (p & 63)) & 1ull);
    out[sidx[p]] = bit ? sscp[p] : 0.0f;
  }
}

extern "C" void kernel_launch(void* const* d_in, const int* in_sizes, int n_in,
                              void* d_out, int out_size, void* d_ws, size_t ws_size,
                              hipStream_t stream) {
  const float* boxes = (const float*)d_in[0];
  const float* scores = (const float*)d_in[1];
  const int* labels = (const int*)d_in[2];
  const float* thr = (const float*)d_in[3];
  float* out = (float*)d_out;

  char* base = (char*)d_ws;
  u32* counters = (u32*)base;                       // 2 u32 (pad 256)
  float* arr = (float*)(base + 256);                // 8 x 2048 f32 = 64 KB
  float* cxp = arr + 0 * NB;
  float* cyp = arr + 1 * NB;
  float* wp = arr + 2 * NB;
  float* hp = arr + 3 * NB;
  float* cp = arr + 4 * NB;
  float* sp = arr + 5 * NB;
  float* radp = arr + 6 * NB;
  float* sscp = arr + 7 * NB;
  int* sidx = (int*)(base + 66048);                 // 8 KB
  u32* edges = (u32*)(base + 81920);                // 64 KB

  build_kernel<<<8, 256, 0, stream>>>(boxes, scores, labels, cxp, cyp, wp, hp,
                                      cp, sp, radp, sscp, sidx, counters);
  candgeom_kernel<<<256, 256, 0, stream>>>(cxp, cyp, wp, hp, cp, sp, radp,
                                           thr, edges, counters);
  greedy_out_kernel<<<1, 256, 0, stream>>>(edges, counters, sscp, sidx, out);
}

// Round 5
// 89.976 us; speedup vs baseline: 2.4124x; 1.5168x over previous
//
#include <hip/hip_runtime.h>
#include <cstdint>

typedef unsigned long long u64;
typedef uint32_t u32;

#define NB 2048
#define EDGE_CAP 16384
#define EDGE_LDS 16384
#define CLIST_CAP 2048

// ---------------------------------------------------------------------------
// Faithful f32 replication of the reference geometry. contract(off) so we
// match XLA's separate mul/add rounding. ALL array indexing is static after
// full unroll -> everything lives in VGPRs (no scratch).
// ---------------------------------------------------------------------------

__device__ __forceinline__ bool pt_in(float px, float py, float cx, float cy,
                                      float hw, float hh, float c, float s) {
#pragma clang fp contract(off)
  float ax = px - cx;
  float ay = py - cy;
  float lx = c * ax + s * ay;
  float ly = c * ay - s * ax;
  return (fabsf(lx) <= hw + 1e-5f) && (fabsf(ly) <= hh + 1e-5f);
}

__device__ float pair_inter_area(float acx, float acy, float aw, float ah,
                                 float ac, float as_, float bcx, float bcy,
                                 float bw, float bh, float bc, float bs_) {
#pragma clang fp contract(off)
  const float SX[4] = {-1.f, 1.f, 1.f, -1.f};
  const float SY[4] = {-1.f, -1.f, 1.f, 1.f};
  float axx[4], ayy[4], bxx[4], byy[4];
  float ahw = aw * 0.5f, ahh = ah * 0.5f;
  float bhw = bw * 0.5f, bhh = bh * 0.5f;
#pragma unroll
  for (int q = 0; q < 4; ++q) {
    float dx = SX[q] * ahw, dy = SY[q] * ahh;
    axx[q] = acx + ac * dx - as_ * dy;
    ayy[q] = acy + as_ * dx + ac * dy;
    float ex = SX[q] * bhw, ey = SY[q] * bhh;
    bxx[q] = bcx + bc * ex - bs_ * ey;
    byy[q] = bcy + bs_ * ex + bc * ey;
  }
  float px_[24], py_[24];
  bool mk[24];
#pragma unroll
  for (int q = 0; q < 4; ++q) {
    px_[q] = axx[q]; py_[q] = ayy[q];
    mk[q] = pt_in(axx[q], ayy[q], bcx, bcy, bhw, bhh, bc, bs_);
    px_[4 + q] = bxx[q]; py_[4 + q] = byy[q];
    mk[4 + q] = pt_in(bxx[q], byy[q], acx, acy, ahw, ahh, ac, as_);
  }
#pragma unroll
  for (int e = 0; e < 4; ++e) {
    float rx = axx[(e + 1) & 3] - axx[e];
    float ry = ayy[(e + 1) & 3] - ayy[e];
#pragma unroll
    for (int f = 0; f < 4; ++f) {
      float sx = bxx[(f + 1) & 3] - bxx[f];
      float sy = byy[(f + 1) & 3] - byy[f];
      float denom = rx * sy - ry * sx;
      float qpx = bxx[f] - axx[e];
      float qpy = byy[f] - ayy[e];
      bool dn = fabsf(denom) > 1e-9f;
      float safe = dn ? denom : 1.0f;
      float t = (qpx * sy - qpy * sx) / safe;
      float uu = (qpx * ry - qpy * rx) / safe;
      bool valid = dn && (t >= 0.0f) && (t <= 1.0f) && (uu >= 0.0f) && (uu <= 1.0f);
      int id = 8 + e * 4 + f;
      px_[id] = axx[e] + t * rx;
      py_[id] = ayy[e] + t * ry;
      mk[id] = valid;
    }
  }
  int k = 0;
  float sx0 = 0.0f, sy0 = 0.0f;
#pragma unroll
  for (int q = 0; q < 24; ++q) {
    if (mk[q]) { k++; sx0 += px_[q]; sy0 += py_[q]; }
  }
  float kk = (float)(k > 0 ? k : 1);
  float cxm = sx0 / kk, cym = sy0 / kk;
  // 32-slot register-resident arrays; slots 24..31 are +inf pads.
  u64 key[32];
  float dxr[32], dyr[32];
#pragma unroll
  for (int q = 0; q < 24; ++q) {
    float dx = px_[q] - cxm, dy = py_[q] - cym;
    dxr[q] = dx; dyr[q] = dy;
    float ang = mk[q] ? atan2f(dy, dx) : 1e9f;
    u32 ub = __float_as_uint(ang);
    u32 v = (ub & 0x80000000u) ? ~ub : (ub | 0x80000000u);
    key[q] = (((u64)v) << 5) | (u64)q;
  }
#pragma unroll
  for (int q = 24; q < 32; ++q) { key[q] = ~0ull; dxr[q] = 0.f; dyr[q] = 0.f; }
  // Bitonic sorting network, ascending by key. All indices compile-time ->
  // pure v_cmp/v_cndmask, zero scratch. Distinct keys => exact stable-argsort
  // permutation of the reference.
#pragma unroll
  for (int kk2 = 2; kk2 <= 32; kk2 <<= 1) {
#pragma unroll
    for (int jj = kk2 >> 1; jj > 0; jj >>= 1) {
#pragma unroll
      for (int ii = 0; ii < 32; ++ii) {
        int ll = ii ^ jj;
        if (ll > ii) {
          bool up = ((ii & kk2) == 0);
          u64 ka = key[ii], kb = key[ll];
          bool sw = up ? (ka > kb) : (ka < kb);
          key[ii] = sw ? kb : ka;
          key[ll] = sw ? ka : kb;
          float da = dxr[ii], db = dxr[ll];
          dxr[ii] = sw ? db : da;
          dxr[ll] = sw ? da : db;
          float ea = dyr[ii], eb = dyr[ll];
          dyr[ii] = sw ? eb : ea;
          dyr[ll] = sw ? ea : eb;
        }
      }
    }
  }
  float acc = 0.0f;
#pragma unroll
  for (int q = 0; q < 24; ++q) {
    if (q < k - 1) {
      acc += dxr[q] * dyr[q + 1] - dyr[q] * dxr[q + 1];
    } else if (q == k - 1) {
      acc += dxr[q] * dyr[0] - dyr[q] * dxr[0];
    }
  }
  float area = 0.5f * fabsf(acc);
  return (k >= 3) ? area : 0.0f;
}

// ---------------------------------------------------------------------------
// A: wave-per-box rank sort. 512 blocks x 4 waves; wave w of block b owns
//    i = b*4+w. Per-block redundant offset_scale reduce; lane-parallel rank
//    scan over LDS scores + shfl reduction; lane 0 writes the SoA row.
// ---------------------------------------------------------------------------
__global__ __launch_bounds__(256) void build_kernel(
    const float* __restrict__ boxes, const float* __restrict__ scores,
    const int* __restrict__ labels,
    float* __restrict__ cxp, float* __restrict__ cyp, float* __restrict__ wp,
    float* __restrict__ hp, float* __restrict__ cp, float* __restrict__ sp,
    float* __restrict__ radp, float* __restrict__ sscp, int* __restrict__ sidx,
    u32* __restrict__ counters) {
#pragma clang fp contract(off)
  __shared__ float sc[NB];
  __shared__ float smc[4], smr[4];
  int t = threadIdx.x;
  if (blockIdx.x == 0 && t < 2) counters[t] = 0u;
  // per-block redundant reduction for offset_scale + scores -> LDS
  float mc = -1e30f, mr = -1e30f;
  for (int k = t; k < NB; k += 256) {
    float cx = boxes[k * 5 + 0];
    float cy = boxes[k * 5 + 1];
    float w = boxes[k * 5 + 2];
    float h = boxes[k * 5 + 3];
    mc = fmaxf(mc, fmaxf(cx, cy));
    float ww = w * w;
    float hh = h * h;
    mr = fmaxf(mr, sqrtf(ww + hh));
    sc[k] = scores[k];
  }
  for (int off = 32; off > 0; off >>= 1) {
    mc = fmaxf(mc, __shfl_down(mc, off));
    mr = fmaxf(mr, __shfl_down(mr, off));
  }
  if ((t & 63) == 0) { smc[t >> 6] = mc; smr[t >> 6] = mr; }
  __syncthreads();
  mc = fmaxf(fmaxf(smc[0], smc[1]), fmaxf(smc[2], smc[3]));
  mr = fmaxf(fmaxf(smr[0], smr[1]), fmaxf(smr[2], smr[3]));
  float osc = (mc + mr * 0.5f) * 2.0f + 1.0f;

  int wave = t >> 6, lane = t & 63;
  int i = blockIdx.x * 4 + wave;
  float si = sc[i];
  int rank = 0;
#pragma unroll 8
  for (int m = 0; m < NB / 64; ++m) {
    int j = m * 64 + lane;
    float sj = sc[j];
    rank += (int)((sj > si) || (sj == si && j < i));
  }
  for (int off = 32; off > 0; off >>= 1) rank += __shfl_down(rank, off);
  if (lane == 0) {
    float off = (float)labels[i] * osc;
    float cx = boxes[i * 5 + 0] + off;
    float cy = boxes[i * 5 + 1] + off;
    float w = boxes[i * 5 + 2];
    float h = boxes[i * 5 + 3];
    float a = boxes[i * 5 + 4];
    float c = cosf(a);
    float s = sinf(a);
    float ww = w * w;
    float hh = h * h;
    cxp[rank] = cx;
    cyp[rank] = cy;
    wp[rank] = w;
    hp[rank] = h;
    cp[rank] = c;
    sp[rank] = s;
    radp[rank] = 0.5f * sqrtf(ww + hh);
    sscp[rank] = si;
    sidx[rank] = i;
  }
}

// ---------------------------------------------------------------------------
// B+C fused: per-block candidate generation (8 rows, circle test from LDS,
// LDS list) then full rotated-IoU on own candidates; edges appended globally.
// ---------------------------------------------------------------------------
__global__ __launch_bounds__(256) void candgeom_kernel(
    const float* __restrict__ cxp, const float* __restrict__ cyp,
    const float* __restrict__ wp, const float* __restrict__ hp,
    const float* __restrict__ cp, const float* __restrict__ sp,
    const float* __restrict__ radp, const float* __restrict__ thrp,
    u32* __restrict__ edges, u32* __restrict__ counters) {
#pragma clang fp contract(off)
  __shared__ float lx[NB], ly[NB], lr[NB];
  __shared__ u32 clist[CLIST_CAP];
  __shared__ u32 ccnt;
  int t = threadIdx.x;
  if (t == 0) ccnt = 0;
  for (int k = t; k < NB; k += 256) {
    lx[k] = cxp[k];
    ly[k] = cyp[k];
    lr[k] = radp[k];
  }
  __syncthreads();
  int i0 = blockIdx.x * 8;
#pragma unroll
  for (int di = 0; di < 8; ++di) {
    int i = i0 + di;
    float ax = lx[i], ay = ly[i], ar = lr[i];
#pragma unroll
    for (int c = 0; c < 8; ++c) {
      int j = c * 256 + t;
      if (j > i) {
        float dx = lx[j] - ax, dy = ly[j] - ay;
        float rr = ar + lr[j] + 1.0f;   // conservative circle pre-test
        if (dx * dx + dy * dy <= rr * rr) {
          u32 s = atomicAdd(&ccnt, 1u);
          if (s < CLIST_CAP) clist[s] = ((u32)i << 16) | (u32)j;
        }
      }
    }
  }
  __syncthreads();
  u32 cnt = ccnt < CLIST_CAP ? ccnt : CLIST_CAP;
  float thr = *thrp;
  for (u32 idx = t; idx < cnt; idx += 256) {
    u32 pk = clist[idx];
    int i = (int)(pk >> 16);
    int j = (int)(pk & 0xFFFFu);
    float acx = cxp[i], acy = cyp[i], aw = wp[i], ah = hp[i];
    float ac = cp[i], as_ = sp[i];
    float bcx = cxp[j], bcy = cyp[j], bw = wp[j], bh = hp[j];
    float bc = cp[j], bs_ = sp[j];
    float inter = pair_inter_area(acx, acy, aw, ah, ac, as_,
                                  bcx, bcy, bw, bh, bc, bs_);
    float areaA = aw * ah;
    float areaB = bw * bh;
    float iou = inter / (areaA + areaB - inter + 1e-9f);
    if (iou > thr) {
      u32 e = atomicAdd(&counters[1], 1u);
      if (e < EDGE_CAP) edges[e] = pk;
    }
  }
}

// ---------------------------------------------------------------------------
// D: greedy keep as parallel fixpoint over the sparse edge list (LDS-staged),
//    then fused output scatter. Antitone F => exact sequential-greedy fixpoint.
// ---------------------------------------------------------------------------
__global__ __launch_bounds__(256) void greedy_out_kernel(
    const u32* __restrict__ edges, const u32* __restrict__ counters,
    const float* __restrict__ sscp, const int* __restrict__ sidx,
    float* __restrict__ out) {
  __shared__ u64 keepw[32];
  __shared__ u32 Sw32[64];
  __shared__ int changed;
  __shared__ u32 eL[EDGE_LDS];
  int t = threadIdx.x;
  u32 ecnt = counters[1];
  if (ecnt > EDGE_CAP) ecnt = EDGE_CAP;
  u32 nl = ecnt < EDGE_LDS ? ecnt : EDGE_LDS;
  for (u32 k = t; k < nl; k += 256) eL[k] = edges[k];
  if (t < 32) keepw[t] = ~0ull;
  __syncthreads();
  for (int iter = 0; iter < 2060; ++iter) {
    if (t < 64) Sw32[t] = 0u;
    if (t == 0) changed = 0;
    __syncthreads();
    for (u32 k = t; k < ecnt; k += 256) {
      u32 pk = (k < EDGE_LDS) ? eL[k] : edges[k];
      int i = (int)(pk >> 16);
      int j = (int)(pk & 0xFFFFu);
      if ((keepw[i >> 6] >> (i & 63)) & 1ull)
        atomicOr(&Sw32[j >> 5], 1u << (j & 31));
    }
    __syncthreads();
    if (t < 32) {
      u64 S = ((u64)Sw32[2 * t]) | (((u64)Sw32[2 * t + 1]) << 32);
      u64 nk = ~S;
      if (nk != keepw[t]) { keepw[t] = nk; changed = 1; }
    }
    __syncthreads();
    int ch = changed;
    __syncthreads();
    if (!ch) break;
  }
  for (int p = t; p < NB; p += 256) {
    int bit = (int)((keepw[p >> 6] >> (p & 63)) & 1ull);
    out[sidx[p]] = bit ? sscp[p] : 0.0f;
  }
}

extern "C" void kernel_launch(void* const* d_in, const int* in_sizes, int n_in,
                              void* d_out, int out_size, void* d_ws, size_t ws_size,
                              hipStream_t stream) {
  const float* boxes = (const float*)d_in[0];
  const float* scores = (const float*)d_in[1];
  const int* labels = (const int*)d_in[2];
  const float* thr = (const float*)d_in[3];
  float* out = (float*)d_out;

  char* base = (char*)d_ws;
  u32* counters = (u32*)base;                       // 2 u32 (pad 256)
  float* arr = (float*)(base + 256);                // 8 x 2048 f32 = 64 KB
  float* cxp = arr + 0 * NB;
  float* cyp = arr + 1 * NB;
  float* wp = arr + 2 * NB;
  float* hp = arr + 3 * NB;
  float* cp = arr + 4 * NB;
  float* sp = arr + 5 * NB;
  float* radp = arr + 6 * NB;
  float* sscp = arr + 7 * NB;
  int* sidx = (int*)(base + 66048);                 // 8 KB
  u32* edges = (u32*)(base + 81920);                // 64 KB

  build_kernel<<<512, 256, 0, stream>>>(boxes, scores, labels, cxp, cyp, wp, hp,
                                        cp, sp, radp, sscp, sidx, counters);
  candgeom_kernel<<<256, 256, 0, stream>>>(cxp, cyp, wp, hp, cp, sp, radp,
                                           thr, edges, counters);
  greedy_out_kernel<<<1, 256, 0, stream>>>(edges, counters, sscp, sidx, out);
}